// Round 13
// baseline (188.067 us; speedup 1.0000x reference)
//
#include <hip/hip_runtime.h>
#include <hip/hip_bf16.h>
#include <math.h>

#define B_   4
#define C_   256
#define H_   56
#define W_   56
#define HW_  3136
#define OC1  128
#define NT   49
#define NP   64          // padded logit count
#define HP_  68          // 56 + 2*6 padded
#define M_TOT 12544      // B_*HW_
#define NSL  14          // K-split slices: 7 tap-rows x 2 cc-halves (4 cc each)

typedef __attribute__((ext_vector_type(8))) short bf16x8;
typedef __attribute__((ext_vector_type(4))) float f32x4;

// ===========================================================================
// FAST PATH: fused-weight bf16 MFMA implicit GEMM (conv2 folded into conv1)
// logits = conv(x, Wf) + cb,  Wf[l,c,tap] = sum_oc W2[l,oc]*W1[oc,c,tap]
// xp2 layout: [cc 8][b 4][hp 68][wp 68][ci 32] bf16   (validated R4-R12)
// wfb layout: [tap 49][cc 8][ntile 4][lane 64][j 8] bf16 fragment order
// kpart: bf16 [slice 14][m 12544][n 64]
// ===========================================================================

// R13: merged prep kernel. Blocks [0,2176): xpack (x -> xp2, validated R4+).
// Blocks [2176,2568): wfuse (Wf fragment pack + cbias, validated R7+).
// Independent memory-bound + VALU-bound work overlaps; one launch removed.
__global__ __launch_bounds__(256) void prep_kernel(const float* __restrict__ x,
                                                   const float* __restrict__ W1,
                                                   const float* __restrict__ W2,
                                                   const float* __restrict__ b1,
                                                   const float* __restrict__ b2,
                                                   __hip_bfloat16* __restrict__ xp,
                                                   __hip_bfloat16* __restrict__ wfb,
                                                   float* __restrict__ cb)
{
    __shared__ char smem[49408];         // union: wfuse 49,408 B / xpack 4,352 B
    int bid = blockIdx.x;
    int tid = threadIdx.x;

    if (bid < 2176) {
        // ---------------- xpack branch (validated xpack2_kernel body) ------
        short* tile = (short*)smem;      // [wp][ci] = 68*32 shorts
        int cc = bid / (B_ * HP_);
        int r  = bid - cc * (B_ * HP_);
        int b  = r / HP_;
        int hp = r - b * HP_;
        int h  = hp - 6;

        if (h < 0 || h >= H_) {
            for (int idx = tid; idx < HP_ * 32; idx += 256) tile[idx] = 0;
        } else {
            int ci = tid >> 3;
            int wg = tid & 7;
            const float* xr = x + ((size_t)(b * C_ + cc * 32 + ci) * H_ + h) * W_;
            #pragma unroll
            for (int k = 0; k < 7; ++k) {
                int w = wg + 8 * k;
                __hip_bfloat16 v = __float2bfloat16(xr[w]);
                tile[(w + 6) * 32 + ci] = *(short*)&v;
            }
            for (int idx = tid; idx < 384; idx += 256) {
                int wp = idx >> 5;
                int wz = (wp < 6) ? wp : (wp + 56);
                tile[wz * 32 + (idx & 31)] = 0;
            }
        }
        __syncthreads();
        short* outp = (short*)xp + ((size_t)((cc * B_ + b) * HP_ + hp) * HP_) * 32;
        for (int idx = tid; idx < 272; idx += 256)
            *(bf16x8*)(outp + idx * 8) = *(bf16x8*)(tile + idx * 8);
    } else {
        // ---------------- wfuse branch (validated wfuse_kernel body) -------
        float* sW2 = (float*)smem;               // [n][oc] stride 129 = 33,024 B
        float* sW1 = (float*)(smem + 33024);     // [oc][ci] = 16,384 B
        int q2  = bid - 2176;                    // 0..391
        int tap = q2 >> 3;                       // 0..48
        int cc  = q2 & 7;                        // 0..7

        for (int idx = tid; idx < NP * 128; idx += 256) {
            int n = idx >> 7, oc = idx & 127;
            sW2[n * 129 + oc] = (n < NT) ? W2[n * 128 + oc] : 0.0f;
        }
        for (int idx = tid; idx < 128 * 32; idx += 256) {
            int oc = idx >> 5, ci = idx & 31;
            sW1[idx] = W1[((size_t)(oc * C_ + cc * 32 + ci)) * NT + tap];
        }
        __syncthreads();

        int ntile = tid >> 6;
        int l     = tid & 63;
        int n     = ntile * 16 + (l & 15);
        int q     = l >> 4;

        float acc[8] = {0,0,0,0,0,0,0,0};
        for (int oc = 0; oc < 128; ++oc) {
            float w2 = sW2[n * 129 + oc];
            const float* r = &sW1[oc * 32 + q * 8];
            #pragma unroll
            for (int j = 0; j < 8; ++j)
                acc[j] += w2 * r[j];
        }

        short pk[8];
        #pragma unroll
        for (int j = 0; j < 8; ++j) {
            __hip_bfloat16 v = __float2bfloat16(acc[j]);
            pk[j] = *(short*)&v;
        }
        short* dst = (short*)wfb + ((size_t)(tap * 8 + cc) * 4 + ntile) * 512 + l * 8;
        *(bf16x8*)dst = *(bf16x8*)pk;

        if (tap == 0 && cc == 0 && tid < 64) {
            float a = 0.0f;
            if (tid < NT) {
                a = b2[tid];
                for (int oc = 0; oc < 128; ++oc)
                    a += sW2[tid * 129 + oc] * b1[oc];
            }
            cb[tid] = a;
        }
    }
}

// Fused conv implicit GEMM (R13): R12 geometry (wave M64xN64, block M256xN64,
// batched A-frags per cc-phase) but B read DIRECTLY from global (L2-resident
// 1.6 MB, L1-hot across the 4 waves) -> zero LDS, zero __syncthreads. One
// continuous 28-step pipeline per block; the 8 barrier drains of R12 are gone.
// Summation order (cc outer, j inner) identical to validated R8-R12.
__global__ __launch_bounds__(256) void conv1_mfma8(const __hip_bfloat16* __restrict__ xp,
                                                   const __hip_bfloat16* __restrict__ wfb,
                                                   __hip_bfloat16* __restrict__ kpart)
{
    const int bid = blockIdx.x;
    const int g   = bid & 7;              // presumed XCD (round-robin dispatch)
    const int kk  = bid >> 3;             // 0..97
    const int s   = (g * 49) >> 3;
    const int cnt = (((g + 1) * 49) >> 3) - s;   // 6 or 7
    const int slice = kk / cnt;           // 0..13 valid
    if (slice >= NSL) return;
    const int mblk = s + (kk - slice * cnt);
    const int m0   = mblk * 256;
    const int i    = slice >> 1;          // tap row 0..6
    const int ch   = slice & 1;           // cc half: cc in [ch*4, ch*4+4)

    const int tid  = threadIdx.x;
    const int lane = tid & 63;
    const int wid  = tid >> 6;            // waveM: wave owns rows m0+wid*64..+63
    const int quad = lane >> 4, l16 = lane & 15;

    const short* xps = (const short*)xp;
    const short* wbs = (const short*)wfb;
    const long CC_STRIDE = (long)B_ * HP_ * HP_ * 32;   // 591,872 elements

    long abase[4];
    #pragma unroll
    for (int mt = 0; mt < 4; ++mt) {
        int m = m0 + wid * 64 + mt * 16 + l16;
        int b = m / HW_; int hw = m - b * HW_;
        int h = hw / W_; int w = hw - h * W_;
        abase[mt] = ((long)(b * HP_ + (h + 2 * i)) * HP_ + w) * 32 + quad * 8;
    }

    f32x4 acc[4][4];
    #pragma unroll
    for (int a = 0; a < 4; ++a)
        #pragma unroll
        for (int b2 = 0; b2 < 4; ++b2) acc[a][b2] = (f32x4){0.f, 0.f, 0.f, 0.f};

    const long lw8 = (long)lane * 8;

    #pragma unroll
    for (int cc4 = 0; cc4 < 4; ++cc4) {
        const int cc = ch * 4 + cc4;
        const long aoffc = (long)cc * CC_STRIDE;

        // batch-issue the whole phase's A loads (28 frags in flight)
        bf16x8 A[7][4];
        #pragma unroll
        for (int j = 0; j < 7; ++j)
            #pragma unroll
            for (int mt = 0; mt < 4; ++mt)
                A[j][mt] = *(const bf16x8*)(xps + abase[mt] + aoffc + (long)j * 64);

        // consume in issue order; B just-in-time from global (L1/L2-hot)
        #pragma unroll
        for (int j = 0; j < 7; ++j) {
            const long boffj = (((long)(i * 7 + j) * 8 + cc) << 11);  // *4nt*512
            bf16x8 bfr[4];
            #pragma unroll
            for (int nt = 0; nt < 4; ++nt)
                bfr[nt] = *(const bf16x8*)(wbs + boffj + ((long)nt << 9) + lw8);
            #pragma unroll
            for (int mt = 0; mt < 4; ++mt)
                #pragma unroll
                for (int nt = 0; nt < 4; ++nt)
                    acc[mt][nt] = __builtin_amdgcn_mfma_f32_16x16x32_bf16(
                        A[j][mt], bfr[nt], acc[mt][nt], 0, 0, 0);
        }
    }

    // Store bf16: C/D layout col(n)=lane&15, row(m)=quad*4+reg (validated)
    #pragma unroll
    for (int mt = 0; mt < 4; ++mt) {
        int mrow = m0 + wid * 64 + mt * 16 + quad * 4;
        #pragma unroll
        for (int nt = 0; nt < 4; ++nt) {
            int n = nt * 16 + l16;
            __hip_bfloat16* dst = kpart + ((long)slice * M_TOT + mrow) * NP + n;
            #pragma unroll
            for (int r = 0; r < 4; ++r)
                dst[(long)r * NP] = __float2bfloat16(acc[mt][nt][r]);
        }
    }
}

// Fold 14 bf16 partial-logit slices + cb, softmax over 49 -> pixel-major attnP.
// One wave per pixel; lane = logit. Coalesced 128 B/wave/slice reads. (validated)
__global__ __launch_bounds__(256) void attn_fold2(const unsigned short* __restrict__ kpart,
                                                  const float* __restrict__ cb,
                                                  float* __restrict__ attnP)
{
    int tid  = threadIdx.x;
    int wid  = tid >> 6;
    int lane = tid & 63;
    int pix  = blockIdx.x * 4 + wid;     // < 12544

    const unsigned short* kp = kpart + (size_t)pix * NP + lane;
    float v = 0.0f;
    #pragma unroll
    for (int sp = 0; sp < NSL; ++sp) {
        unsigned int u = (unsigned int)kp[(size_t)sp * M_TOT * NP] << 16;
        v += __uint_as_float(u);
    }

    float logit = (lane < NT) ? (v + cb[lane]) : -INFINITY;
    float mx = logit;
    for (int s = 32; s > 0; s >>= 1) mx = fmaxf(mx, __shfl_xor(mx, s, 64));
    float e = (lane < NT) ? __expf(logit - mx) : 0.0f;
    float sum = e;
    for (int s = 32; s > 0; s >>= 1) sum += __shfl_xor(sum, s, 64);
    if (lane < NT)
        attnP[(size_t)pix * NT + lane] = e / sum;
}

// Weighted 49-tap gather (validated R10-R12): granule-major sX [i][cg4][wp][c4]
// -> conflict-free b128 main loop; XCD-swizzled bh blocks.
__global__ __launch_bounds__(256) void out_kernel4(const float* __restrict__ x,
                                                   const float* __restrict__ attnP,
                                                   float* __restrict__ out)
{
    __shared__ float sX[7 * 4 * HP_ * 4]; // [i][cg4][wp][c4] 30.5 KB
    __shared__ float sA[56 * NT];         // [w][l] 10.7 KB

    int bid = blockIdx.x;                // < 3584
    int g   = bid & 7;                   // presumed XCD
    int s   = bid >> 3;                  // 0..447
    int bh  = g * 28 + (s % 28);         // 28 bh-rows per XCD slot
    int cg  = s / 28;                    // 0..15
    int b   = bh / H_;
    int h   = bh - b * H_;
    int c0  = cg * 16;
    int tid = threadIdx.x;

    for (int idx = tid; idx < 7 * 4 * HP_ * 4; idx += 256)
        sX[idx] = 0.0f;
    __syncthreads();

    {
        const float* ap = attnP + ((size_t)(b * HW_) + h * W_) * NT;
        for (int idx = tid; idx < W_ * NT; idx += 256)
            sA[idx] = ap[idx];
    }
    {
        int c  = tid >> 4;
        int wg = tid & 15;
        const float* xc = x + (size_t)(b * C_ + c0 + c) * HW_;
        int cgr = c >> 2, ce = c & 3;
        #pragma unroll
        for (int i = 0; i < 7; ++i) {
            int ih = h + 2 * i - 6;
            if (ih < 0 || ih >= H_) continue;
            const float* xr = xc + ih * W_;
            #pragma unroll
            for (int k = 0; k < 4; ++k) {
                int w = wg + 16 * k;
                if (w < W_)
                    sX[(((i * 4 + cgr) * HP_) + (w + 6)) * 4 + ce] = xr[w];
            }
        }
    }
    __syncthreads();

    int lane = tid & 63;
    int wid  = tid >> 6;                 // wave -> channels c0+wid*4 .. +3
    int w    = lane;
    bool active = (w < W_);
    int wc = active ? w : (W_ - 1);

    float aR[NT];
    #pragma unroll
    for (int l = 0; l < NT; ++l)
        aR[l] = sA[wc * NT + l];

    f32x4 acc = (f32x4){0.f, 0.f, 0.f, 0.f};
    #pragma unroll
    for (int i = 0; i < 7; ++i) {
        const float* sXi = &sX[(i * 4 + wid) * HP_ * 4];
        #pragma unroll
        for (int j = 0; j < 7; ++j) {
            f32x4 xv = *(const f32x4*)&sXi[(wc + 2 * j) * 4];
            float a = aR[i * 7 + j];
            acc.x += a * xv.x; acc.y += a * xv.y;
            acc.z += a * xv.z; acc.w += a * xv.w;
        }
    }

    if (active) {
        size_t o = ((size_t)(b * C_ + c0 + wid * 4)) * HW_ + h * W_ + w;
        out[o + 0 * HW_] = acc.x;
        out[o + 1 * HW_] = acc.y;
        out[o + 2 * HW_] = acc.z;
        out[o + 3 * HW_] = acc.w;
    }
}

// ===========================================================================
// FALLBACK PATH (R1, proven): used only if ws_size < fast-path need
// ===========================================================================
__global__ __launch_bounds__(256) void wt_kernel(const float* __restrict__ W1,
                                                 float* __restrict__ wT)
{
    int idx = blockIdx.x * 256 + threadIdx.x;
    int oc = idx & 127;
    int ct = idx >> 7;
    wT[idx] = W1[oc * (C_ * NT) + ct];
}

__global__ __launch_bounds__(256) void conv1_kernel(const float* __restrict__ x,
                                                    const float* __restrict__ wT,
                                                    const float* __restrict__ b1,
                                                    float* __restrict__ k)
{
    int tid = threadIdx.x;
    int w   = tid & 63;
    int ty  = tid >> 6;
    int h   = blockIdx.x * 4 + ty;
    int oc0 = blockIdx.y * 8;
    int b   = blockIdx.z;

    const float* xb = x + (size_t)b * C_ * HW_;
    float acc[8] = {0.f,0.f,0.f,0.f,0.f,0.f,0.f,0.f};

    for (int i = 0; i < 7; ++i) {
        int ih = h + 2 * i - 6;
        if (ih < 0 || ih >= H_) continue;
        for (int j = 0; j < 7; ++j) {
            int iw = w + 2 * j - 6;
            bool v  = (iw >= 0) && (iw < W_);
            float m = v ? 1.0f : 0.0f;
            const float* xr = xb + ih * W_ + (v ? iw : 0);
            const float* wr = wT + (size_t)(i * 7 + j) * OC1 + oc0;
            #pragma unroll 4
            for (int c = 0; c < C_; ++c) {
                float xv = m * xr[(size_t)c * HW_];
                const float4 w0 = *(const float4*)(wr + (size_t)c * NT * OC1);
                const float4 w1 = *(const float4*)(wr + (size_t)c * NT * OC1 + 4);
                acc[0] += xv * w0.x; acc[1] += xv * w0.y;
                acc[2] += xv * w0.z; acc[3] += xv * w0.w;
                acc[4] += xv * w1.x; acc[5] += xv * w1.y;
                acc[6] += xv * w1.z; acc[7] += xv * w1.w;
            }
        }
    }
    if (w < W_) {
        size_t o = ((size_t)(b * OC1 + oc0)) * HW_ + h * W_ + w;
        #pragma unroll
        for (int q = 0; q < 8; ++q)
            k[o + (size_t)q * HW_] = acc[q] + b1[oc0 + q];
    }
}

__global__ __launch_bounds__(256) void attn_kernel(const float* __restrict__ kin,
                                                   const float* __restrict__ W2,
                                                   const float* __restrict__ b2,
                                                   float* __restrict__ attn)
{
    __shared__ float sW2[128 * 49];
    int tid = threadIdx.x;
    for (int idx = tid; idx < 128 * 49; idx += 256) {
        int c = idx / 49, l = idx - c * 49;
        sW2[idx] = W2[l * 128 + c];
    }
    __syncthreads();

    int wid  = tid >> 6;
    int lane = tid & 63;
    int pix  = blockIdx.x * 4 + wid;
    int b    = pix / HW_;
    int hw   = pix - b * HW_;
    int l    = (lane < 49) ? lane : 0;

    const float* kb = kin + (size_t)b * OC1 * HW_ + hw;
    float acc = b2[l];
    #pragma unroll 8
    for (int c = 0; c < 128; ++c)
        acc += kb[(size_t)c * HW_] * sW2[c * 49 + l];

    float logit = (lane < 49) ? acc : -INFINITY;
    float mx = logit;
    for (int s = 32; s > 0; s >>= 1) mx = fmaxf(mx, __shfl_xor(mx, s, 64));
    float e = (lane < 49) ? __expf(logit - mx) : 0.0f;
    float sum = e;
    for (int s = 32; s > 0; s >>= 1) sum += __shfl_xor(sum, s, 64);
    if (lane < 49)
        attn[((size_t)b * NT + lane) * HW_ + hw] = e / sum;
}

__global__ __launch_bounds__(256) void out_kernel(const float* __restrict__ x,
                                                  const float* __restrict__ attn,
                                                  float* __restrict__ out)
{
    int idx = blockIdx.x * 256 + threadIdx.x;
    int w  = idx % 56;
    int t  = idx / 56;
    int h  = t % 56;
    int t2 = t / 56;
    int c  = t2 & 255;
    int b  = t2 >> 8;

    const float* xb = x + (size_t)(b * C_ + c) * HW_;
    const float* ab = attn + (size_t)b * NT * HW_ + h * W_ + w;

    float acc = 0.f;
    #pragma unroll
    for (int i = 0; i < 7; ++i) {
        int ih = h + 2 * i - 6;
        bool hv = (ih >= 0) && (ih < H_);
        #pragma unroll
        for (int j = 0; j < 7; ++j) {
            int iw = w + 2 * j - 6;
            bool v  = hv && (iw >= 0) && (iw < W_);
            float m = v ? 1.0f : 0.0f;
            int off = v ? (ih * W_ + iw) : 0;
            acc += (m * xb[off]) * ab[(size_t)(i * 7 + j) * HW_];
        }
    }
    out[idx] = acc;
}

// ===========================================================================
extern "C" void kernel_launch(void* const* d_in, const int* in_sizes, int n_in,
                              void* d_out, int out_size, void* d_ws, size_t ws_size,
                              hipStream_t stream)
{
    const float* x  = (const float*)d_in[0];
    const float* W1 = (const float*)d_in[1];
    const float* b1 = (const float*)d_in[2];
    const float* W2 = (const float*)d_in[3];
    const float* b2 = (const float*)d_in[4];
    float* out = (float*)d_out;

    // fast-path ws layout (bytes)
    const size_t xp_b    = (size_t)B_ * HP_ * HP_ * 256 * 2;        //  9,469,952
    const size_t wfb_b   = (size_t)NT * 8 * 4 * 64 * 8 * 2;         //  1,605,632
    const size_t kpart_b = (size_t)NSL * M_TOT * NP * 2;            // 22,478,848 (bf16)
    const size_t attn_b  = (size_t)M_TOT * NT * 4;                  //  2,458,624
    const size_t cb_b    = 256;
    const size_t need = xp_b + wfb_b + kpart_b + attn_b + cb_b;     // ~36.0 MB

    if (ws_size >= need) {
        char* base = (char*)d_ws;
        __hip_bfloat16* xp    = (__hip_bfloat16*)base;
        __hip_bfloat16* wfb   = (__hip_bfloat16*)(base + xp_b);
        __hip_bfloat16* kpart = (__hip_bfloat16*)(base + xp_b + wfb_b);
        float* attnP = (float*)(base + xp_b + wfb_b + kpart_b);
        float* cb    = (float*)(base + xp_b + wfb_b + kpart_b + attn_b);

        prep_kernel  <<<2568, 256, 0, stream>>>(x, W1, W2, b1, b2, xp, wfb, cb);
        conv1_mfma8  <<<784, 256, 0, stream>>>(xp, wfb, kpart);
        attn_fold2   <<<3136, 256, 0, stream>>>((const unsigned short*)kpart, cb, attnP);
        out_kernel4  <<<3584, 256, 0, stream>>>(x, attnP, out);
    } else {
        // R1 fallback (~14.6 MB)
        float* wT   = (float*)d_ws;
        float* kbuf = wT + 1605632;
        float* attn = kbuf + 1605632;
        wt_kernel   <<<6272, 256, 0, stream>>>(W1, wT);
        conv1_kernel<<<dim3(14, 16, 4), 256, 0, stream>>>(x, wT, b1, kbuf);
        attn_kernel <<<3136, 256, 0, stream>>>(kbuf, W2, b2, attn);
        out_kernel  <<<12544, 256, 0, stream>>>(x, attn, out);
    }
}

// Round 14
// 176.817 us; speedup vs baseline: 1.0636x; 1.0636x over previous
//
#include <hip/hip_runtime.h>
#include <hip/hip_bf16.h>
#include <math.h>

#define B_   4
#define C_   256
#define H_   56
#define W_   56
#define HW_  3136
#define OC1  128
#define NT   49
#define NP   64          // padded logit count
#define HP_  68          // 56 + 2*6 padded
#define M_TOT 12544      // B_*HW_
#define NSL  14          // K-split slices: 7 tap-rows x 2 cc-halves (4 cc each)

typedef __attribute__((ext_vector_type(8))) short bf16x8;
typedef __attribute__((ext_vector_type(4))) float f32x4;

// ===========================================================================
// FAST PATH: fused-weight bf16 MFMA implicit GEMM (conv2 folded into conv1)
// logits = conv(x, Wf) + cb,  Wf[l,c,tap] = sum_oc W2[l,oc]*W1[oc,c,tap]
// xp2 layout: [cc 8][b 4][hp 68][wp 68][ci 32] bf16   (validated R4-R13)
// wfb layout: [tap 49][cc 8][ntile 4][lane 64][j 8] bf16 fragment order
// kpart: bf16 [slice 14][m 12544][n 64]
// ===========================================================================

// Merged prep kernel (validated R13). Blocks [0,2176): xpack (x -> xp2).
// Blocks [2176,2568): wfuse (Wf fragment pack + cbias).
__global__ __launch_bounds__(256) void prep_kernel(const float* __restrict__ x,
                                                   const float* __restrict__ W1,
                                                   const float* __restrict__ W2,
                                                   const float* __restrict__ b1,
                                                   const float* __restrict__ b2,
                                                   __hip_bfloat16* __restrict__ xp,
                                                   __hip_bfloat16* __restrict__ wfb,
                                                   float* __restrict__ cb)
{
    __shared__ char smem[49408];         // union: wfuse 49,408 B / xpack 4,352 B
    int bid = blockIdx.x;
    int tid = threadIdx.x;

    if (bid < 2176) {
        // ---------------- xpack branch (validated xpack2_kernel body) ------
        short* tile = (short*)smem;      // [wp][ci] = 68*32 shorts
        int cc = bid / (B_ * HP_);
        int r  = bid - cc * (B_ * HP_);
        int b  = r / HP_;
        int hp = r - b * HP_;
        int h  = hp - 6;

        if (h < 0 || h >= H_) {
            for (int idx = tid; idx < HP_ * 32; idx += 256) tile[idx] = 0;
        } else {
            int ci = tid >> 3;
            int wg = tid & 7;
            const float* xr = x + ((size_t)(b * C_ + cc * 32 + ci) * H_ + h) * W_;
            #pragma unroll
            for (int k = 0; k < 7; ++k) {
                int w = wg + 8 * k;
                __hip_bfloat16 v = __float2bfloat16(xr[w]);
                tile[(w + 6) * 32 + ci] = *(short*)&v;
            }
            for (int idx = tid; idx < 384; idx += 256) {
                int wp = idx >> 5;
                int wz = (wp < 6) ? wp : (wp + 56);
                tile[wz * 32 + (idx & 31)] = 0;
            }
        }
        __syncthreads();
        short* outp = (short*)xp + ((size_t)((cc * B_ + b) * HP_ + hp) * HP_) * 32;
        for (int idx = tid; idx < 272; idx += 256)
            *(bf16x8*)(outp + idx * 8) = *(bf16x8*)(tile + idx * 8);
    } else {
        // ---------------- wfuse branch (validated wfuse_kernel body) -------
        float* sW2 = (float*)smem;               // [n][oc] stride 129 = 33,024 B
        float* sW1 = (float*)(smem + 33024);     // [oc][ci] = 16,384 B
        int q2  = bid - 2176;                    // 0..391
        int tap = q2 >> 3;                       // 0..48
        int cc  = q2 & 7;                        // 0..7

        for (int idx = tid; idx < NP * 128; idx += 256) {
            int n = idx >> 7, oc = idx & 127;
            sW2[n * 129 + oc] = (n < NT) ? W2[n * 128 + oc] : 0.0f;
        }
        for (int idx = tid; idx < 128 * 32; idx += 256) {
            int oc = idx >> 5, ci = idx & 31;
            sW1[idx] = W1[((size_t)(oc * C_ + cc * 32 + ci)) * NT + tap];
        }
        __syncthreads();

        int ntile = tid >> 6;
        int l     = tid & 63;
        int n     = ntile * 16 + (l & 15);
        int q     = l >> 4;

        float acc[8] = {0,0,0,0,0,0,0,0};
        for (int oc = 0; oc < 128; ++oc) {
            float w2 = sW2[n * 129 + oc];
            const float* r = &sW1[oc * 32 + q * 8];
            #pragma unroll
            for (int j = 0; j < 8; ++j)
                acc[j] += w2 * r[j];
        }

        short pk[8];
        #pragma unroll
        for (int j = 0; j < 8; ++j) {
            __hip_bfloat16 v = __float2bfloat16(acc[j]);
            pk[j] = *(short*)&v;
        }
        short* dst = (short*)wfb + ((size_t)(tap * 8 + cc) * 4 + ntile) * 512 + l * 8;
        *(bf16x8*)dst = *(bf16x8*)pk;

        if (tap == 0 && cc == 0 && tid < 64) {
            float a = 0.0f;
            if (tid < NT) {
                a = b2[tid];
                for (int oc = 0; oc < 128; ++oc)
                    a += sW2[tid * 129 + oc] * b1[oc];
            }
            cb[tid] = a;
        }
    }
}

// Fused conv implicit GEMM — R12-validated KEEPER (conv1_mfma7): wave M64xN64,
// block M256xN64, B(i,cc) staged in LDS (28 KB) per cc-phase, and ALL 28
// A-frags batch-issued before MFMA consumption (rolling vmcnt). R13's
// barrier-free direct-global-B variant regressed to 54 us (VMEM-issue wall);
// this structure keeps B on the LDS pipe and A batched -> <43 us measured.
__global__ __launch_bounds__(256) void conv1_mfma7(const __hip_bfloat16* __restrict__ xp,
                                                   const __hip_bfloat16* __restrict__ wfb,
                                                   __hip_bfloat16* __restrict__ kpart)
{
    __shared__ short sB[28 * 512];        // [j7][nt4][lane64][8] = 28 KB

    const int bid = blockIdx.x;
    const int g   = bid & 7;              // presumed XCD (round-robin dispatch)
    const int kk  = bid >> 3;             // 0..97
    const int s   = (g * 49) >> 3;
    const int cnt = (((g + 1) * 49) >> 3) - s;   // 6 or 7
    const int slice = kk / cnt;           // 0..13 valid
    if (slice >= NSL) return;
    const int mblk = s + (kk - slice * cnt);
    const int m0   = mblk * 256;
    const int i    = slice >> 1;          // tap row 0..6
    const int ch   = slice & 1;           // cc half: cc in [ch*4, ch*4+4)

    const int tid  = threadIdx.x;
    const int lane = tid & 63;
    const int wid  = tid >> 6;            // waveM: wave owns rows m0+wid*64..+63
    const int quad = lane >> 4, l16 = lane & 15;

    const short* xps = (const short*)xp;
    const short* wbs = (const short*)wfb;
    const long CC_STRIDE = (long)B_ * HP_ * HP_ * 32;   // 591,872 elements

    long abase[4];
    #pragma unroll
    for (int mt = 0; mt < 4; ++mt) {
        int m = m0 + wid * 64 + mt * 16 + l16;
        int b = m / HW_; int hw = m - b * HW_;
        int h = hw / W_; int w = hw - h * W_;
        abase[mt] = ((long)(b * HP_ + (h + 2 * i)) * HP_ + w) * 32 + quad * 8;
    }

    f32x4 acc[4][4];
    #pragma unroll
    for (int a = 0; a < 4; ++a)
        #pragma unroll
        for (int b2 = 0; b2 < 4; ++b2) acc[a][b2] = (f32x4){0.f, 0.f, 0.f, 0.f};

    #pragma unroll
    for (int cc4 = 0; cc4 < 4; ++cc4) {
        const int cc = ch * 4 + cc4;
        __syncthreads();                  // guard prev phase's reads vs restage
        // stage B(i,cc): 28 chunks of 512 shorts; wave w does q = w + 4k
        #pragma unroll
        for (int k = 0; k < 7; ++k) {
            int q = wid + 4 * k;          // 0..27
            int j = q >> 2, nt = q & 3;
            const short* src = wbs + ((((long)(i * 7 + j) * 8 + cc) * 4 + nt) << 9) + lane * 8;
            bf16x8 v = *(const bf16x8*)src;
            *(bf16x8*)(&sB[q * 512 + lane * 8]) = v;
        }
        __syncthreads();

        const long aoffc = (long)cc * CC_STRIDE;
        // batch-issue the whole phase's A loads (28 frags in flight)
        bf16x8 A[7][4];
        #pragma unroll
        for (int j = 0; j < 7; ++j)
            #pragma unroll
            for (int mt = 0; mt < 4; ++mt)
                A[j][mt] = *(const bf16x8*)(xps + abase[mt] + aoffc + (long)j * 64);
        // consume in issue order -> rolling vmcnt
        #pragma unroll
        for (int j = 0; j < 7; ++j) {
            bf16x8 bfr[4];
            #pragma unroll
            for (int nt = 0; nt < 4; ++nt)
                bfr[nt] = *(const bf16x8*)(&sB[(j * 4 + nt) * 512 + lane * 8]);
            #pragma unroll
            for (int mt = 0; mt < 4; ++mt)
                #pragma unroll
                for (int nt = 0; nt < 4; ++nt)
                    acc[mt][nt] = __builtin_amdgcn_mfma_f32_16x16x32_bf16(
                        A[j][mt], bfr[nt], acc[mt][nt], 0, 0, 0);
        }
    }

    // Store bf16: C/D layout col(n)=lane&15, row(m)=quad*4+reg (validated)
    #pragma unroll
    for (int mt = 0; mt < 4; ++mt) {
        int mrow = m0 + wid * 64 + mt * 16 + quad * 4;
        #pragma unroll
        for (int nt = 0; nt < 4; ++nt) {
            int n = nt * 16 + l16;
            __hip_bfloat16* dst = kpart + ((long)slice * M_TOT + mrow) * NP + n;
            #pragma unroll
            for (int r = 0; r < 4; ++r)
                dst[(long)r * NP] = __float2bfloat16(acc[mt][nt][r]);
        }
    }
}

// Fold 14 bf16 partial-logit slices + cb, softmax over 49 -> pixel-major attnP.
// One wave per pixel; lane = logit. Coalesced 128 B/wave/slice reads. (validated)
__global__ __launch_bounds__(256) void attn_fold2(const unsigned short* __restrict__ kpart,
                                                  const float* __restrict__ cb,
                                                  float* __restrict__ attnP)
{
    int tid  = threadIdx.x;
    int wid  = tid >> 6;
    int lane = tid & 63;
    int pix  = blockIdx.x * 4 + wid;     // < 12544

    const unsigned short* kp = kpart + (size_t)pix * NP + lane;
    float v = 0.0f;
    #pragma unroll
    for (int sp = 0; sp < NSL; ++sp) {
        unsigned int u = (unsigned int)kp[(size_t)sp * M_TOT * NP] << 16;
        v += __uint_as_float(u);
    }

    float logit = (lane < NT) ? (v + cb[lane]) : -INFINITY;
    float mx = logit;
    for (int s = 32; s > 0; s >>= 1) mx = fmaxf(mx, __shfl_xor(mx, s, 64));
    float e = (lane < NT) ? __expf(logit - mx) : 0.0f;
    float sum = e;
    for (int s = 32; s > 0; s >>= 1) sum += __shfl_xor(sum, s, 64);
    if (lane < NT)
        attnP[(size_t)pix * NT + lane] = e / sum;
}

// Weighted 49-tap gather (validated R10-R13): granule-major sX [i][cg4][wp][c4]
// -> conflict-free b128 main loop; XCD-swizzled bh blocks.
__global__ __launch_bounds__(256) void out_kernel4(const float* __restrict__ x,
                                                   const float* __restrict__ attnP,
                                                   float* __restrict__ out)
{
    __shared__ float sX[7 * 4 * HP_ * 4]; // [i][cg4][wp][c4] 30.5 KB
    __shared__ float sA[56 * NT];         // [w][l] 10.7 KB

    int bid = blockIdx.x;                // < 3584
    int g   = bid & 7;                   // presumed XCD
    int s   = bid >> 3;                  // 0..447
    int bh  = g * 28 + (s % 28);         // 28 bh-rows per XCD slot
    int cg  = s / 28;                    // 0..15
    int b   = bh / H_;
    int h   = bh - b * H_;
    int c0  = cg * 16;
    int tid = threadIdx.x;

    for (int idx = tid; idx < 7 * 4 * HP_ * 4; idx += 256)
        sX[idx] = 0.0f;
    __syncthreads();

    {
        const float* ap = attnP + ((size_t)(b * HW_) + h * W_) * NT;
        for (int idx = tid; idx < W_ * NT; idx += 256)
            sA[idx] = ap[idx];
    }
    {
        int c  = tid >> 4;
        int wg = tid & 15;
        const float* xc = x + (size_t)(b * C_ + c0 + c) * HW_;
        int cgr = c >> 2, ce = c & 3;
        #pragma unroll
        for (int i = 0; i < 7; ++i) {
            int ih = h + 2 * i - 6;
            if (ih < 0 || ih >= H_) continue;
            const float* xr = xc + ih * W_;
            #pragma unroll
            for (int k = 0; k < 4; ++k) {
                int w = wg + 16 * k;
                if (w < W_)
                    sX[(((i * 4 + cgr) * HP_) + (w + 6)) * 4 + ce] = xr[w];
            }
        }
    }
    __syncthreads();

    int lane = tid & 63;
    int wid  = tid >> 6;                 // wave -> channels c0+wid*4 .. +3
    int w    = lane;
    bool active = (w < W_);
    int wc = active ? w : (W_ - 1);

    float aR[NT];
    #pragma unroll
    for (int l = 0; l < NT; ++l)
        aR[l] = sA[wc * NT + l];

    f32x4 acc = (f32x4){0.f, 0.f, 0.f, 0.f};
    #pragma unroll
    for (int i = 0; i < 7; ++i) {
        const float* sXi = &sX[(i * 4 + wid) * HP_ * 4];
        #pragma unroll
        for (int j = 0; j < 7; ++j) {
            f32x4 xv = *(const f32x4*)&sXi[(wc + 2 * j) * 4];
            float a = aR[i * 7 + j];
            acc.x += a * xv.x; acc.y += a * xv.y;
            acc.z += a * xv.z; acc.w += a * xv.w;
        }
    }

    if (active) {
        size_t o = ((size_t)(b * C_ + c0 + wid * 4)) * HW_ + h * W_ + w;
        out[o + 0 * HW_] = acc.x;
        out[o + 1 * HW_] = acc.y;
        out[o + 2 * HW_] = acc.z;
        out[o + 3 * HW_] = acc.w;
    }
}

// ===========================================================================
// FALLBACK PATH (R1, proven): used only if ws_size < fast-path need
// ===========================================================================
__global__ __launch_bounds__(256) void wt_kernel(const float* __restrict__ W1,
                                                 float* __restrict__ wT)
{
    int idx = blockIdx.x * 256 + threadIdx.x;
    int oc = idx & 127;
    int ct = idx >> 7;
    wT[idx] = W1[oc * (C_ * NT) + ct];
}

__global__ __launch_bounds__(256) void conv1_kernel(const float* __restrict__ x,
                                                    const float* __restrict__ wT,
                                                    const float* __restrict__ b1,
                                                    float* __restrict__ k)
{
    int tid = threadIdx.x;
    int w   = tid & 63;
    int ty  = tid >> 6;
    int h   = blockIdx.x * 4 + ty;
    int oc0 = blockIdx.y * 8;
    int b   = blockIdx.z;

    const float* xb = x + (size_t)b * C_ * HW_;
    float acc[8] = {0.f,0.f,0.f,0.f,0.f,0.f,0.f,0.f};

    for (int i = 0; i < 7; ++i) {
        int ih = h + 2 * i - 6;
        if (ih < 0 || ih >= H_) continue;
        for (int j = 0; j < 7; ++j) {
            int iw = w + 2 * j - 6;
            bool v  = (iw >= 0) && (iw < W_);
            float m = v ? 1.0f : 0.0f;
            const float* xr = xb + ih * W_ + (v ? iw : 0);
            const float* wr = wT + (size_t)(i * 7 + j) * OC1 + oc0;
            #pragma unroll 4
            for (int c = 0; c < C_; ++c) {
                float xv = m * xr[(size_t)c * HW_];
                const float4 w0 = *(const float4*)(wr + (size_t)c * NT * OC1);
                const float4 w1 = *(const float4*)(wr + (size_t)c * NT * OC1 + 4);
                acc[0] += xv * w0.x; acc[1] += xv * w0.y;
                acc[2] += xv * w0.z; acc[3] += xv * w0.w;
                acc[4] += xv * w1.x; acc[5] += xv * w1.y;
                acc[6] += xv * w1.z; acc[7] += xv * w1.w;
            }
        }
    }
    if (w < W_) {
        size_t o = ((size_t)(b * OC1 + oc0)) * HW_ + h * W_ + w;
        #pragma unroll
        for (int q = 0; q < 8; ++q)
            k[o + (size_t)q * HW_] = acc[q] + b1[oc0 + q];
    }
}

__global__ __launch_bounds__(256) void attn_kernel(const float* __restrict__ kin,
                                                   const float* __restrict__ W2,
                                                   const float* __restrict__ b2,
                                                   float* __restrict__ attn)
{
    __shared__ float sW2[128 * 49];
    int tid = threadIdx.x;
    for (int idx = tid; idx < 128 * 49; idx += 256) {
        int c = idx / 49, l = idx - c * 49;
        sW2[idx] = W2[l * 128 + c];
    }
    __syncthreads();

    int wid  = tid >> 6;
    int lane = tid & 63;
    int pix  = blockIdx.x * 4 + wid;
    int b    = pix / HW_;
    int hw   = pix - b * HW_;
    int l    = (lane < 49) ? lane : 0;

    const float* kb = kin + (size_t)b * OC1 * HW_ + hw;
    float acc = b2[l];
    #pragma unroll 8
    for (int c = 0; c < 128; ++c)
        acc += kb[(size_t)c * HW_] * sW2[c * 49 + l];

    float logit = (lane < 49) ? acc : -INFINITY;
    float mx = logit;
    for (int s = 32; s > 0; s >>= 1) mx = fmaxf(mx, __shfl_xor(mx, s, 64));
    float e = (lane < 49) ? __expf(logit - mx) : 0.0f;
    float sum = e;
    for (int s = 32; s > 0; s >>= 1) sum += __shfl_xor(sum, s, 64);
    if (lane < 49)
        attn[((size_t)b * NT + lane) * HW_ + hw] = e / sum;
}

__global__ __launch_bounds__(256) void out_kernel(const float* __restrict__ x,
                                                  const float* __restrict__ attn,
                                                  float* __restrict__ out)
{
    int idx = blockIdx.x * 256 + threadIdx.x;
    int w  = idx % 56;
    int t  = idx / 56;
    int h  = t % 56;
    int t2 = t / 56;
    int c  = t2 & 255;
    int b  = t2 >> 8;

    const float* xb = x + (size_t)(b * C_ + c) * HW_;
    const float* ab = attn + (size_t)b * NT * HW_ + h * W_ + w;

    float acc = 0.f;
    #pragma unroll
    for (int i = 0; i < 7; ++i) {
        int ih = h + 2 * i - 6;
        bool hv = (ih >= 0) && (ih < H_);
        #pragma unroll
        for (int j = 0; j < 7; ++j) {
            int iw = w + 2 * j - 6;
            bool v  = hv && (iw >= 0) && (iw < W_);
            float m = v ? 1.0f : 0.0f;
            int off = v ? (ih * W_ + iw) : 0;
            acc += (m * xb[off]) * ab[(size_t)(i * 7 + j) * HW_];
        }
    }
    out[idx] = acc;
}

// ===========================================================================
extern "C" void kernel_launch(void* const* d_in, const int* in_sizes, int n_in,
                              void* d_out, int out_size, void* d_ws, size_t ws_size,
                              hipStream_t stream)
{
    const float* x  = (const float*)d_in[0];
    const float* W1 = (const float*)d_in[1];
    const float* b1 = (const float*)d_in[2];
    const float* W2 = (const float*)d_in[3];
    const float* b2 = (const float*)d_in[4];
    float* out = (float*)d_out;

    // fast-path ws layout (bytes)
    const size_t xp_b    = (size_t)B_ * HP_ * HP_ * 256 * 2;        //  9,469,952
    const size_t wfb_b   = (size_t)NT * 8 * 4 * 64 * 8 * 2;         //  1,605,632
    const size_t kpart_b = (size_t)NSL * M_TOT * NP * 2;            // 22,478,848 (bf16)
    const size_t attn_b  = (size_t)M_TOT * NT * 4;                  //  2,458,624
    const size_t cb_b    = 256;
    const size_t need = xp_b + wfb_b + kpart_b + attn_b + cb_b;     // ~36.0 MB

    if (ws_size >= need) {
        char* base = (char*)d_ws;
        __hip_bfloat16* xp    = (__hip_bfloat16*)base;
        __hip_bfloat16* wfb   = (__hip_bfloat16*)(base + xp_b);
        __hip_bfloat16* kpart = (__hip_bfloat16*)(base + xp_b + wfb_b);
        float* attnP = (float*)(base + xp_b + wfb_b + kpart_b);
        float* cb    = (float*)(base + xp_b + wfb_b + kpart_b + attn_b);

        prep_kernel  <<<2568, 256, 0, stream>>>(x, W1, W2, b1, b2, xp, wfb, cb);
        conv1_mfma7  <<<784, 256, 0, stream>>>(xp, wfb, kpart);
        attn_fold2   <<<3136, 256, 0, stream>>>((const unsigned short*)kpart, cb, attnP);
        out_kernel4  <<<3584, 256, 0, stream>>>(x, attnP, out);
    } else {
        // R1 fallback (~14.6 MB)
        float* wT   = (float*)d_ws;
        float* kbuf = wT + 1605632;
        float* attn = kbuf + 1605632;
        wt_kernel   <<<6272, 256, 0, stream>>>(W1, wT);
        conv1_kernel<<<dim3(14, 16, 4), 256, 0, stream>>>(x, wT, b1, kbuf);
        attn_kernel <<<3136, 256, 0, stream>>>(kbuf, W2, b2, attn);
        out_kernel  <<<12544, 256, 0, stream>>>(x, attn, out);
    }
}

// Round 15
// 176.173 us; speedup vs baseline: 1.0675x; 1.0037x over previous
//
#include <hip/hip_runtime.h>
#include <hip/hip_bf16.h>
#include <math.h>

#define B_   4
#define C_   256
#define H_   56
#define W_   56
#define HW_  3136
#define OC1  128
#define NT   49
#define NP   64          // padded logit count
#define HP_  68          // 56 + 2*6 padded
#define M_TOT 12544      // B_*HW_
#define NSL  14          // K-split slices: 7 tap-rows x 2 cc-halves (4 cc each)

typedef __attribute__((ext_vector_type(8))) short bf16x8;
typedef __attribute__((ext_vector_type(4))) float f32x4;

// ===========================================================================
// FAST PATH: fused-weight bf16 MFMA implicit GEMM (conv2 folded into conv1)
// logits = conv(x, Wf) + cb,  Wf[l,c,tap] = sum_oc W2[l,oc]*W1[oc,c,tap]
// xp2 layout: [cc 8][b 4][hp 68][wp 68][ci 32] bf16   (validated R4-R14)
// wfb layout: [tap 49][cc 8][ntile 4][lane 64][j 8] bf16 fragment order
// kpart: bf16 [slice 14][m 12544][n 64]
// ===========================================================================

// Merged prep kernel (validated R13/R14). Blocks [0,2176): xpack (x -> xp2).
// Blocks [2176,2568): wfuse (Wf fragment pack + cbias).
__global__ __launch_bounds__(256) void prep_kernel(const float* __restrict__ x,
                                                   const float* __restrict__ W1,
                                                   const float* __restrict__ W2,
                                                   const float* __restrict__ b1,
                                                   const float* __restrict__ b2,
                                                   __hip_bfloat16* __restrict__ xp,
                                                   __hip_bfloat16* __restrict__ wfb,
                                                   float* __restrict__ cb)
{
    __shared__ char smem[49408];         // union: wfuse 49,408 B / xpack 4,352 B
    int bid = blockIdx.x;
    int tid = threadIdx.x;

    if (bid < 2176) {
        // ---------------- xpack branch (validated xpack2_kernel body) ------
        short* tile = (short*)smem;      // [wp][ci] = 68*32 shorts
        int cc = bid / (B_ * HP_);
        int r  = bid - cc * (B_ * HP_);
        int b  = r / HP_;
        int hp = r - b * HP_;
        int h  = hp - 6;

        if (h < 0 || h >= H_) {
            for (int idx = tid; idx < HP_ * 32; idx += 256) tile[idx] = 0;
        } else {
            int ci = tid >> 3;
            int wg = tid & 7;
            const float* xr = x + ((size_t)(b * C_ + cc * 32 + ci) * H_ + h) * W_;
            #pragma unroll
            for (int k = 0; k < 7; ++k) {
                int w = wg + 8 * k;
                __hip_bfloat16 v = __float2bfloat16(xr[w]);
                tile[(w + 6) * 32 + ci] = *(short*)&v;
            }
            for (int idx = tid; idx < 384; idx += 256) {
                int wp = idx >> 5;
                int wz = (wp < 6) ? wp : (wp + 56);
                tile[wz * 32 + (idx & 31)] = 0;
            }
        }
        __syncthreads();
        short* outp = (short*)xp + ((size_t)((cc * B_ + b) * HP_ + hp) * HP_) * 32;
        for (int idx = tid; idx < 272; idx += 256)
            *(bf16x8*)(outp + idx * 8) = *(bf16x8*)(tile + idx * 8);
    } else {
        // ---------------- wfuse branch (validated wfuse_kernel body) -------
        float* sW2 = (float*)smem;               // [n][oc] stride 129 = 33,024 B
        float* sW1 = (float*)(smem + 33024);     // [oc][ci] = 16,384 B
        int q2  = bid - 2176;                    // 0..391
        int tap = q2 >> 3;                       // 0..48
        int cc  = q2 & 7;                        // 0..7

        for (int idx = tid; idx < NP * 128; idx += 256) {
            int n = idx >> 7, oc = idx & 127;
            sW2[n * 129 + oc] = (n < NT) ? W2[n * 128 + oc] : 0.0f;
        }
        for (int idx = tid; idx < 128 * 32; idx += 256) {
            int oc = idx >> 5, ci = idx & 31;
            sW1[idx] = W1[((size_t)(oc * C_ + cc * 32 + ci)) * NT + tap];
        }
        __syncthreads();

        int ntile = tid >> 6;
        int l     = tid & 63;
        int n     = ntile * 16 + (l & 15);
        int q     = l >> 4;

        float acc[8] = {0,0,0,0,0,0,0,0};
        for (int oc = 0; oc < 128; ++oc) {
            float w2 = sW2[n * 129 + oc];
            const float* r = &sW1[oc * 32 + q * 8];
            #pragma unroll
            for (int j = 0; j < 8; ++j)
                acc[j] += w2 * r[j];
        }

        short pk[8];
        #pragma unroll
        for (int j = 0; j < 8; ++j) {
            __hip_bfloat16 v = __float2bfloat16(acc[j]);
            pk[j] = *(short*)&v;
        }
        short* dst = (short*)wfb + ((size_t)(tap * 8 + cc) * 4 + ntile) * 512 + l * 8;
        *(bf16x8*)dst = *(bf16x8*)pk;

        if (tap == 0 && cc == 0 && tid < 64) {
            float a = 0.0f;
            if (tid < NT) {
                a = b2[tid];
                for (int oc = 0; oc < 128; ++oc)
                    a += sW2[tid * 129 + oc] * b1[oc];
            }
            cb[tid] = a;
        }
    }
}

// Fused conv implicit GEMM (R15): R12 keeper geometry (wave M64xN64, block
// M256xN64, batched A-frags, B via LDS) + DOUBLE-BUFFERED sB: next phase's
// B-chunk is prefetched into registers under the current phase's MFMAs and
// ds_written to the alternate buffer -> ONE barrier per phase (4/block vs 8),
// and the remaining barriers sit after consumption with no in-flight A-batch
// to drain. Summation order (cc outer, j inner) identical to R8-R14.
__global__ __launch_bounds__(256) void conv1_mfma9(const __hip_bfloat16* __restrict__ xp,
                                                   const __hip_bfloat16* __restrict__ wfb,
                                                   __hip_bfloat16* __restrict__ kpart)
{
    __shared__ short sB[2][28 * 512];     // double buffer: 2 x 28 KB

    const int bid = blockIdx.x;
    const int g   = bid & 7;              // presumed XCD (round-robin dispatch)
    const int kk  = bid >> 3;             // 0..97
    const int s   = (g * 49) >> 3;
    const int cnt = (((g + 1) * 49) >> 3) - s;   // 6 or 7
    const int slice = kk / cnt;           // 0..13 valid
    if (slice >= NSL) return;
    const int mblk = s + (kk - slice * cnt);
    const int m0   = mblk * 256;
    const int i    = slice >> 1;          // tap row 0..6
    const int ch   = slice & 1;           // cc half: cc in [ch*4, ch*4+4)

    const int tid  = threadIdx.x;
    const int lane = tid & 63;
    const int wid  = tid >> 6;            // waveM: wave owns rows m0+wid*64..+63
    const int quad = lane >> 4, l16 = lane & 15;

    const short* xps = (const short*)xp;
    const short* wbs = (const short*)wfb;
    const long CC_STRIDE = (long)B_ * HP_ * HP_ * 32;   // 591,872 elements
    const long lw8 = (long)lane * 8;

    long abase[4];
    #pragma unroll
    for (int mt = 0; mt < 4; ++mt) {
        int m = m0 + wid * 64 + mt * 16 + l16;
        int b = m / HW_; int hw = m - b * HW_;
        int h = hw / W_; int w = hw - h * W_;
        abase[mt] = ((long)(b * HP_ + (h + 2 * i)) * HP_ + w) * 32 + quad * 8;
    }

    f32x4 acc[4][4];
    #pragma unroll
    for (int a = 0; a < 4; ++a)
        #pragma unroll
        for (int b2 = 0; b2 < 4; ++b2) acc[a][b2] = (f32x4){0.f, 0.f, 0.f, 0.f};

    // B-chunk register prefetch helper offsets: wave w stages q = wid + 4k
    // (q -> j = q>>2, nt = q&3), 7 chunks of 512 shorts per wave.
    bf16x8 Breg[7];
    {
        const int cc0 = ch * 4;
        #pragma unroll
        for (int k = 0; k < 7; ++k) {
            int q = wid + 4 * k;
            int j = q >> 2, nt = q & 3;
            Breg[k] = *(const bf16x8*)(wbs + ((((long)(i * 7 + j) * 8 + cc0) * 4 + nt) << 9) + lw8);
        }
        #pragma unroll
        for (int k = 0; k < 7; ++k) {
            int q = wid + 4 * k;
            *(bf16x8*)(&sB[0][q * 512 + lw8]) = Breg[k];
        }
    }
    __syncthreads();

    #pragma unroll
    for (int ph = 0; ph < 4; ++ph) {
        const int cc  = ch * 4 + ph;
        const int cur = ph & 1;
        const long aoffc = (long)cc * CC_STRIDE;

        // prefetch NEXT phase's B into registers (L2-hot; drains early)
        if (ph < 3) {
            const int ccn = cc + 1;
            #pragma unroll
            for (int k = 0; k < 7; ++k) {
                int q = wid + 4 * k;
                int j = q >> 2, nt = q & 3;
                Breg[k] = *(const bf16x8*)(wbs + ((((long)(i * 7 + j) * 8 + ccn) * 4 + nt) << 9) + lw8);
            }
        }

        // batch-issue the whole phase's A loads (28 frags in flight)
        bf16x8 A[7][4];
        #pragma unroll
        for (int j = 0; j < 7; ++j)
            #pragma unroll
            for (int mt = 0; mt < 4; ++mt)
                A[j][mt] = *(const bf16x8*)(xps + abase[mt] + aoffc + (long)j * 64);

        // consume in issue order -> rolling vmcnt
        #pragma unroll
        for (int j = 0; j < 7; ++j) {
            bf16x8 bfr[4];
            #pragma unroll
            for (int nt = 0; nt < 4; ++nt)
                bfr[nt] = *(const bf16x8*)(&sB[cur][(j * 4 + nt) * 512 + lw8]);
            #pragma unroll
            for (int mt = 0; mt < 4; ++mt)
                #pragma unroll
                for (int nt = 0; nt < 4; ++nt)
                    acc[mt][nt] = __builtin_amdgcn_mfma_f32_16x16x32_bf16(
                        A[j][mt], bfr[nt], acc[mt][nt], 0, 0, 0);
        }

        // write prefetched B into the alternate buffer; one barrier per phase.
        // Safe: buf[cur^1] was last READ in phase ph-1, barrier since.
        if (ph < 3) {
            #pragma unroll
            for (int k = 0; k < 7; ++k) {
                int q = wid + 4 * k;
                *(bf16x8*)(&sB[cur ^ 1][q * 512 + lw8]) = Breg[k];
            }
            __syncthreads();
        }
    }

    // Store bf16: C/D layout col(n)=lane&15, row(m)=quad*4+reg (validated)
    #pragma unroll
    for (int mt = 0; mt < 4; ++mt) {
        int mrow = m0 + wid * 64 + mt * 16 + quad * 4;
        #pragma unroll
        for (int nt = 0; nt < 4; ++nt) {
            int n = nt * 16 + l16;
            __hip_bfloat16* dst = kpart + ((long)slice * M_TOT + mrow) * NP + n;
            #pragma unroll
            for (int r = 0; r < 4; ++r)
                dst[(long)r * NP] = __float2bfloat16(acc[mt][nt][r]);
        }
    }
}

// Fold 14 bf16 partial-logit slices + cb, softmax over 49 -> pixel-major attnP.
// One wave per pixel; lane = logit. Coalesced 128 B/wave/slice reads. (validated)
__global__ __launch_bounds__(256) void attn_fold2(const unsigned short* __restrict__ kpart,
                                                  const float* __restrict__ cb,
                                                  float* __restrict__ attnP)
{
    int tid  = threadIdx.x;
    int wid  = tid >> 6;
    int lane = tid & 63;
    int pix  = blockIdx.x * 4 + wid;     // < 12544

    const unsigned short* kp = kpart + (size_t)pix * NP + lane;
    float v = 0.0f;
    #pragma unroll
    for (int sp = 0; sp < NSL; ++sp) {
        unsigned int u = (unsigned int)kp[(size_t)sp * M_TOT * NP] << 16;
        v += __uint_as_float(u);
    }

    float logit = (lane < NT) ? (v + cb[lane]) : -INFINITY;
    float mx = logit;
    for (int s = 32; s > 0; s >>= 1) mx = fmaxf(mx, __shfl_xor(mx, s, 64));
    float e = (lane < NT) ? __expf(logit - mx) : 0.0f;
    float sum = e;
    for (int s = 32; s > 0; s >>= 1) sum += __shfl_xor(sum, s, 64);
    if (lane < NT)
        attnP[(size_t)pix * NT + lane] = e / sum;
}

// Weighted 49-tap gather (validated R10-R14): granule-major sX [i][cg4][wp][c4]
// -> conflict-free b128 main loop; XCD-swizzled bh blocks.
__global__ __launch_bounds__(256) void out_kernel4(const float* __restrict__ x,
                                                   const float* __restrict__ attnP,
                                                   float* __restrict__ out)
{
    __shared__ float sX[7 * 4 * HP_ * 4]; // [i][cg4][wp][c4] 30.5 KB
    __shared__ float sA[56 * NT];         // [w][l] 10.7 KB

    int bid = blockIdx.x;                // < 3584
    int g   = bid & 7;                   // presumed XCD
    int s   = bid >> 3;                  // 0..447
    int bh  = g * 28 + (s % 28);         // 28 bh-rows per XCD slot
    int cg  = s / 28;                    // 0..15
    int b   = bh / H_;
    int h   = bh - b * H_;
    int c0  = cg * 16;
    int tid = threadIdx.x;

    for (int idx = tid; idx < 7 * 4 * HP_ * 4; idx += 256)
        sX[idx] = 0.0f;
    __syncthreads();

    {
        const float* ap = attnP + ((size_t)(b * HW_) + h * W_) * NT;
        for (int idx = tid; idx < W_ * NT; idx += 256)
            sA[idx] = ap[idx];
    }
    {
        int c  = tid >> 4;
        int wg = tid & 15;
        const float* xc = x + (size_t)(b * C_ + c0 + c) * HW_;
        int cgr = c >> 2, ce = c & 3;
        #pragma unroll
        for (int i = 0; i < 7; ++i) {
            int ih = h + 2 * i - 6;
            if (ih < 0 || ih >= H_) continue;
            const float* xr = xc + ih * W_;
            #pragma unroll
            for (int k = 0; k < 4; ++k) {
                int w = wg + 16 * k;
                if (w < W_)
                    sX[(((i * 4 + cgr) * HP_) + (w + 6)) * 4 + ce] = xr[w];
            }
        }
    }
    __syncthreads();

    int lane = tid & 63;
    int wid  = tid >> 6;                 // wave -> channels c0+wid*4 .. +3
    int w    = lane;
    bool active = (w < W_);
    int wc = active ? w : (W_ - 1);

    float aR[NT];
    #pragma unroll
    for (int l = 0; l < NT; ++l)
        aR[l] = sA[wc * NT + l];

    f32x4 acc = (f32x4){0.f, 0.f, 0.f, 0.f};
    #pragma unroll
    for (int i = 0; i < 7; ++i) {
        const float* sXi = &sX[(i * 4 + wid) * HP_ * 4];
        #pragma unroll
        for (int j = 0; j < 7; ++j) {
            f32x4 xv = *(const f32x4*)&sXi[(wc + 2 * j) * 4];
            float a = aR[i * 7 + j];
            acc.x += a * xv.x; acc.y += a * xv.y;
            acc.z += a * xv.z; acc.w += a * xv.w;
        }
    }

    if (active) {
        size_t o = ((size_t)(b * C_ + c0 + wid * 4)) * HW_ + h * W_ + w;
        out[o + 0 * HW_] = acc.x;
        out[o + 1 * HW_] = acc.y;
        out[o + 2 * HW_] = acc.z;
        out[o + 3 * HW_] = acc.w;
    }
}

// ===========================================================================
// FALLBACK PATH (R1, proven): used only if ws_size < fast-path need
// ===========================================================================
__global__ __launch_bounds__(256) void wt_kernel(const float* __restrict__ W1,
                                                 float* __restrict__ wT)
{
    int idx = blockIdx.x * 256 + threadIdx.x;
    int oc = idx & 127;
    int ct = idx >> 7;
    wT[idx] = W1[oc * (C_ * NT) + ct];
}

__global__ __launch_bounds__(256) void conv1_kernel(const float* __restrict__ x,
                                                    const float* __restrict__ wT,
                                                    const float* __restrict__ b1,
                                                    float* __restrict__ k)
{
    int tid = threadIdx.x;
    int w   = tid & 63;
    int ty  = tid >> 6;
    int h   = blockIdx.x * 4 + ty;
    int oc0 = blockIdx.y * 8;
    int b   = blockIdx.z;

    const float* xb = x + (size_t)b * C_ * HW_;
    float acc[8] = {0.f,0.f,0.f,0.f,0.f,0.f,0.f,0.f};

    for (int i = 0; i < 7; ++i) {
        int ih = h + 2 * i - 6;
        if (ih < 0 || ih >= H_) continue;
        for (int j = 0; j < 7; ++j) {
            int iw = w + 2 * j - 6;
            bool v  = (iw >= 0) && (iw < W_);
            float m = v ? 1.0f : 0.0f;
            const float* xr = xb + ih * W_ + (v ? iw : 0);
            const float* wr = wT + (size_t)(i * 7 + j) * OC1 + oc0;
            #pragma unroll 4
            for (int c = 0; c < C_; ++c) {
                float xv = m * xr[(size_t)c * HW_];
                const float4 w0 = *(const float4*)(wr + (size_t)c * NT * OC1);
                const float4 w1 = *(const float4*)(wr + (size_t)c * NT * OC1 + 4);
                acc[0] += xv * w0.x; acc[1] += xv * w0.y;
                acc[2] += xv * w0.z; acc[3] += xv * w0.w;
                acc[4] += xv * w1.x; acc[5] += xv * w1.y;
                acc[6] += xv * w1.z; acc[7] += xv * w1.w;
            }
        }
    }
    if (w < W_) {
        size_t o = ((size_t)(b * OC1 + oc0)) * HW_ + h * W_ + w;
        #pragma unroll
        for (int q = 0; q < 8; ++q)
            k[o + (size_t)q * HW_] = acc[q] + b1[oc0 + q];
    }
}

__global__ __launch_bounds__(256) void attn_kernel(const float* __restrict__ kin,
                                                   const float* __restrict__ W2,
                                                   const float* __restrict__ b2,
                                                   float* __restrict__ attn)
{
    __shared__ float sW2[128 * 49];
    int tid = threadIdx.x;
    for (int idx = tid; idx < 128 * 49; idx += 256) {
        int c = idx / 49, l = idx - c * 49;
        sW2[idx] = W2[l * 128 + c];
    }
    __syncthreads();

    int wid  = tid >> 6;
    int lane = tid & 63;
    int pix  = blockIdx.x * 4 + wid;
    int b    = pix / HW_;
    int hw   = pix - b * HW_;
    int l    = (lane < 49) ? lane : 0;

    const float* kb = kin + (size_t)b * OC1 * HW_ + hw;
    float acc = b2[l];
    #pragma unroll 8
    for (int c = 0; c < 128; ++c)
        acc += kb[(size_t)c * HW_] * sW2[c * 49 + l];

    float logit = (lane < 49) ? acc : -INFINITY;
    float mx = logit;
    for (int s = 32; s > 0; s >>= 1) mx = fmaxf(mx, __shfl_xor(mx, s, 64));
    float e = (lane < 49) ? __expf(logit - mx) : 0.0f;
    float sum = e;
    for (int s = 32; s > 0; s >>= 1) sum += __shfl_xor(sum, s, 64);
    if (lane < 49)
        attn[((size_t)b * NT + lane) * HW_ + hw] = e / sum;
}

__global__ __launch_bounds__(256) void out_kernel(const float* __restrict__ x,
                                                  const float* __restrict__ attn,
                                                  float* __restrict__ out)
{
    int idx = blockIdx.x * 256 + threadIdx.x;
    int w  = idx % 56;
    int t  = idx / 56;
    int h  = t % 56;
    int t2 = t / 56;
    int c  = t2 & 255;
    int b  = t2 >> 8;

    const float* xb = x + (size_t)(b * C_ + c) * HW_;
    const float* ab = attn + (size_t)b * NT * HW_ + h * W_ + w;

    float acc = 0.f;
    #pragma unroll
    for (int i = 0; i < 7; ++i) {
        int ih = h + 2 * i - 6;
        bool hv = (ih >= 0) && (ih < H_);
        #pragma unroll
        for (int j = 0; j < 7; ++j) {
            int iw = w + 2 * j - 6;
            bool v  = hv && (iw >= 0) && (iw < W_);
            float m = v ? 1.0f : 0.0f;
            int off = v ? (ih * W_ + iw) : 0;
            acc += (m * xb[off]) * ab[(size_t)(i * 7 + j) * HW_];
        }
    }
    out[idx] = acc;
}

// ===========================================================================
extern "C" void kernel_launch(void* const* d_in, const int* in_sizes, int n_in,
                              void* d_out, int out_size, void* d_ws, size_t ws_size,
                              hipStream_t stream)
{
    const float* x  = (const float*)d_in[0];
    const float* W1 = (const float*)d_in[1];
    const float* b1 = (const float*)d_in[2];
    const float* W2 = (const float*)d_in[3];
    const float* b2 = (const float*)d_in[4];
    float* out = (float*)d_out;

    // fast-path ws layout (bytes)
    const size_t xp_b    = (size_t)B_ * HP_ * HP_ * 256 * 2;        //  9,469,952
    const size_t wfb_b   = (size_t)NT * 8 * 4 * 64 * 8 * 2;         //  1,605,632
    const size_t kpart_b = (size_t)NSL * M_TOT * NP * 2;            // 22,478,848 (bf16)
    const size_t attn_b  = (size_t)M_TOT * NT * 4;                  //  2,458,624
    const size_t cb_b    = 256;
    const size_t need = xp_b + wfb_b + kpart_b + attn_b + cb_b;     // ~36.0 MB

    if (ws_size >= need) {
        char* base = (char*)d_ws;
        __hip_bfloat16* xp    = (__hip_bfloat16*)base;
        __hip_bfloat16* wfb   = (__hip_bfloat16*)(base + xp_b);
        __hip_bfloat16* kpart = (__hip_bfloat16*)(base + xp_b + wfb_b);
        float* attnP = (float*)(base + xp_b + wfb_b + kpart_b);
        float* cb    = (float*)(base + xp_b + wfb_b + kpart_b + attn_b);

        prep_kernel  <<<2568, 256, 0, stream>>>(x, W1, W2, b1, b2, xp, wfb, cb);
        conv1_mfma9  <<<784, 256, 0, stream>>>(xp, wfb, kpart);
        attn_fold2   <<<3136, 256, 0, stream>>>((const unsigned short*)kpart, cb, attnP);
        out_kernel4  <<<3584, 256, 0, stream>>>(x, attnP, out);
    } else {
        // R1 fallback (~14.6 MB)
        float* wT   = (float*)d_ws;
        float* kbuf = wT + 1605632;
        float* attn = kbuf + 1605632;
        wt_kernel   <<<6272, 256, 0, stream>>>(W1, wT);
        conv1_kernel<<<dim3(14, 16, 4), 256, 0, stream>>>(x, wT, b1, kbuf);
        attn_kernel <<<3136, 256, 0, stream>>>(kbuf, W2, b2, attn);
        out_kernel  <<<12544, 256, 0, stream>>>(x, attn, out);
    }
}